// Round 9
// baseline (102.901 us; speedup 1.0000x reference)
//
#include <hip/hip_runtime.h>
#include <hip/hip_bf16.h>

// ---------------- constants ----------------
#define B_SZ 2
#define L_SZ 512
#define D_MODEL 512
#define D_INNER 1024
#define HEAD_DIM 64
#define NHEADS 16
#define D_STATE 64
#define D_CONV 3
#define CONV_DIM 1152            // D_INNER + 2*D_STATE
#define D_IN_PROJ 2192           // 2*D_INNER + 2*D_STATE + NHEADS
#define BL (B_SZ * L_SZ)         // 1024
#define RMS_EPS 1e-5f
#define QC 64                    // SSD chunk length
#define NCH 8                    // chunks per batch (L_SZ/QC)
#define NPAD1 2304               // W_in^T padded rows (36*64)
#define PB 72                    // bf16 LDS pitch (144B rows: frag reads 2-way = free)
#define NBLK 256u                // mega-kernel grid (<= 256 CUs -> co-resident)

typedef __attribute__((ext_vector_type(8))) short short8t;
typedef __attribute__((ext_vector_type(8))) unsigned short ushort8t;
typedef __attribute__((ext_vector_type(4))) unsigned short ushort4t;
typedef __attribute__((ext_vector_type(4))) float f32x4;

__device__ __forceinline__ unsigned short f2bf(float f) {
    unsigned u = __float_as_uint(f);
    u += 0x7fff + ((u >> 16) & 1);          // round-to-nearest-even
    return (unsigned short)(u >> 16);
}
__device__ __forceinline__ float bf2f(unsigned short u) {
    return __uint_as_float(((unsigned)u) << 16);
}

__device__ __forceinline__ void gload_lds16(const void* g, void* lds) {
    __builtin_amdgcn_global_load_lds(
        (const __attribute__((address_space(1))) unsigned int*)g,
        (__attribute__((address_space(3))) unsigned int*)lds, 16, 0, 0);
}

// grid-wide barrier: counters pre-zeroed by prep each launch (stream-ordered).
// __syncthreads drains each wave's vmcnt(0) -> all block stores retired;
// RELEASE/ACQUIRE at AGENT scope handle cross-XCD L2 visibility.
__device__ __forceinline__ void grid_barrier(unsigned* cnt, int k) {
    __syncthreads();
    if (threadIdx.x == 0) {
        __hip_atomic_fetch_add(&cnt[k], 1u, __ATOMIC_RELEASE, __HIP_MEMORY_SCOPE_AGENT);
        while (__hip_atomic_load(&cnt[k], __ATOMIC_ACQUIRE, __HIP_MEMORY_SCOPE_AGENT) < NBLK)
            __builtin_amdgcn_s_sleep(2);
    }
    __syncthreads();
}

// ---------------- prep: W_in -> Wt1[2304][512] bf16, W_out -> Wt2[512][1024] bf16, u -> bf16
__device__ __forceinline__ void transpose_tile_bf16(const float* __restrict__ src,
                                                    unsigned short* __restrict__ dst,
                                                    int K, int Nin, int tile, int ntn) {
    __shared__ float T[64][65];
    int tid = threadIdx.x;
    int nt = tile % ntn, kt = tile / ntn;
    int n0 = nt * 64, k0 = kt * 64;
#pragma unroll
    for (int rr = 0; rr < 4; ++rr) {
        int k = k0 + (tid >> 4) + rr * 16;
        int nn = (tid & 15) * 4;
#pragma unroll
        for (int q = 0; q < 4; ++q) {
            int n = n0 + nn + q;
            T[(tid >> 4) + rr * 16][nn + q] = (n < Nin) ? src[(size_t)k * Nin + n] : 0.f;
        }
    }
    __syncthreads();
    int nn2 = tid >> 2, kc = tid & 3;
    unsigned short ov[16];
#pragma unroll
    for (int j = 0; j < 16; ++j) ov[j] = f2bf(T[kc * 16 + j][nn2]);
    unsigned short* p = dst + (size_t)(n0 + nn2) * K + k0 + kc * 16;
    *(ushort8t*)p = *(ushort8t*)&ov[0];
    *(ushort8t*)(p + 8) = *(ushort8t*)&ov[8];
}

__global__ __launch_bounds__(256) void prep_kernel(const float* __restrict__ W_in,
                                                   const float* __restrict__ W_out,
                                                   const float* __restrict__ u,
                                                   unsigned short* __restrict__ Wt1,
                                                   unsigned short* __restrict__ Wt2,
                                                   unsigned short* __restrict__ u_bf,
                                                   unsigned* __restrict__ cnt) {
    int bid = blockIdx.x;
    if (bid == 0 && threadIdx.x < 8) cnt[threadIdx.x] = 0u;   // reset barrier counters
    if (bid < 288) {
        transpose_tile_bf16(W_in, Wt1, D_MODEL, D_IN_PROJ, bid, 36);
    } else if (bid < 416) {
        transpose_tile_bf16(W_out, Wt2, D_INNER, D_MODEL, bid - 288, 8);
    } else {
        int i = ((bid - 416) * 256 + threadIdx.x) * 8;
        float4 v0 = *(const float4*)(u + i);
        float4 v1 = *(const float4*)(u + i + 4);
        unsigned short ov[8] = {f2bf(v0.x), f2bf(v0.y), f2bf(v0.z), f2bf(v0.w),
                                f2bf(v1.x), f2bf(v1.y), f2bf(v1.z), f2bf(v1.w)};
        *(ushort8t*)(u_bf + i) = *(ushort8t*)&ov[0];
    }
}

// ---------------- bf16 MFMA GEMM 64x64 (in_proj): C[M,N] = A[M,K] * Bt[N,K]^T ----------------
__global__ __launch_bounds__(256) void gemm_mfma64(const unsigned short* __restrict__ A,
                                                   const unsigned short* __restrict__ Bt,
                                                   float* __restrict__ C,
                                                   int N, int K) {
    __shared__ char sm[49152];          // 3 buf x (A:8192 | B:8192)
    int tid = threadIdx.x;
    int w = tid >> 6, l = tid & 63;
    int m0 = blockIdx.y * 64, n0 = blockIdx.x * 64;
    int wm = w >> 1, wn = w & 1;

    f32x4 acc[2][2];
#pragma unroll
    for (int i = 0; i < 2; ++i)
#pragma unroll
        for (int j = 0; j < 2; ++j) acc[i][j] = (f32x4){0.f, 0.f, 0.f, 0.f};

    auto stage = [&](const unsigned short* src, int row0, int k0, char* dst) {
#pragma unroll
        for (int p = 0; p < 2; ++p) {
            int c = w * 2 + p;
            int row = c * 8 + (l >> 3);
            int scb = ((l & 7) << 4) ^ ((row & 7) << 4);
            gload_lds16(src + (size_t)(row0 + row) * K + k0 + (scb >> 1), dst + c * 1024);
        }
    };

    int nkt = K / 64;
    stage(A, m0, 0, sm);
    stage(Bt, n0, 0, sm + 8192);
    if (nkt > 1) {
        stage(A, m0, 64, sm + 16384);
        stage(Bt, n0, 64, sm + 16384 + 8192);
    }

    for (int kt = 0; kt < nkt; ++kt) {
        if (kt + 2 < nkt) {
            char* d = sm + ((kt + 2) % 3) * 16384;
            stage(A, m0, (kt + 2) * 64, d);
            stage(Bt, n0, (kt + 2) * 64, d + 8192);
        }
        int inflight = nkt - 1 - kt;
        if (inflight >= 2)      asm volatile("s_waitcnt vmcnt(8)" ::: "memory");
        else if (inflight == 1) asm volatile("s_waitcnt vmcnt(4)" ::: "memory");
        else                    asm volatile("s_waitcnt vmcnt(0)" ::: "memory");
        __builtin_amdgcn_s_barrier();

        const char* Ab = sm + (kt % 3) * 16384;
        const char* Bb = Ab + 8192;
#pragma unroll
        for (int kk = 0; kk < 2; ++kk) {
            short8t af[2], bf[2];
#pragma unroll
            for (int i = 0; i < 2; ++i) {
                int r = wm * 32 + i * 16 + (l & 15);
                int cb = (kk * 64 + (l >> 4) * 16) ^ ((r & 7) << 4);
                af[i] = *(const short8t*)(Ab + r * 128 + cb);
            }
#pragma unroll
            for (int j = 0; j < 2; ++j) {
                int r = wn * 32 + j * 16 + (l & 15);
                int cb = (kk * 64 + (l >> 4) * 16) ^ ((r & 7) << 4);
                bf[j] = *(const short8t*)(Bb + r * 128 + cb);
            }
#pragma unroll
            for (int i = 0; i < 2; ++i)
#pragma unroll
                for (int j = 0; j < 2; ++j)
                    acc[i][j] = __builtin_amdgcn_mfma_f32_16x16x32_bf16(af[i], bf[j], acc[i][j], 0, 0, 0);
        }
        __builtin_amdgcn_s_barrier();
    }

#pragma unroll
    for (int i = 0; i < 2; ++i)
#pragma unroll
        for (int j = 0; j < 2; ++j) {
            int row = m0 + wm * 32 + i * 16 + (l >> 4) * 4;
            int col = n0 + wn * 32 + j * 16 + (l & 15);
            if (col < N) {
#pragma unroll
                for (int r = 0; r < 4; ++r)
                    C[(size_t)(row + r) * N + col] = acc[i][j][r];
            }
        }
}

// conv+SiLU of 4 consecutive channels at one row; gl = seq position (causal clamp)
__device__ __forceinline__ float4 conv4(const float* __restrict__ prow, int gl, int zxcol,
                                        const float* __restrict__ conv_w,
                                        const float* __restrict__ conv_b) {
    float4 v2 = *(const float4*)(prow + zxcol);
    float4 v1 = make_float4(0.f, 0.f, 0.f, 0.f), v0 = v1;
    if (gl >= 1) v1 = *(const float4*)(prow - D_IN_PROJ + zxcol);
    if (gl >= 2) v0 = *(const float4*)(prow - 2 * D_IN_PROJ + zxcol);
    int ch = zxcol - D_INNER;
    float4 o;
    float a;
    a = conv_b[ch+0] + conv_w[(ch+0)*3]*v0.x + conv_w[(ch+0)*3+1]*v1.x + conv_w[(ch+0)*3+2]*v2.x;
    o.x = a / (1.f + __expf(-a));
    a = conv_b[ch+1] + conv_w[(ch+1)*3]*v0.y + conv_w[(ch+1)*3+1]*v1.y + conv_w[(ch+1)*3+2]*v2.y;
    o.y = a / (1.f + __expf(-a));
    a = conv_b[ch+2] + conv_w[(ch+2)*3]*v0.z + conv_w[(ch+2)*3+1]*v1.z + conv_w[(ch+2)*3+2]*v2.z;
    o.z = a / (1.f + __expf(-a));
    a = conv_b[ch+3] + conv_w[(ch+3)*3]*v0.w + conv_w[(ch+3)*3+1]*v1.w + conv_w[(ch+3)*3+2]*v2.w;
    o.w = a / (1.f + __expf(-a));
    return o;
}

// ---------------- mega phase bodies (inlined; smem aliased per phase) ----------------

__device__ __forceinline__ void passA_body(int blk, int tid, char* smem,
        const float* __restrict__ zxbcdt, const float* __restrict__ conv_w,
        const float* __restrict__ conv_b, const float* __restrict__ dt_bias,
        const float* __restrict__ A_log, const float* __restrict__ D_param,
        float* __restrict__ y, float* __restrict__ Zbuf, float* __restrict__ Ebuf) {
    int h = blk & 15;
    int c = (blk >> 4) & 7;
    int b = blk >> 7;

    unsigned short* Cs  = (unsigned short*)smem;            // [64][72]; reused as P
    unsigned short* Bs  = Cs + 64 * PB;
    unsigned short* XDT = Bs + 64 * PB;
    unsigned short* BTw = XDT + 64 * PB;
    float* csh = (float*)(smem + 4 * 64 * PB * 2);
    float* dts = csh + 64;
    float* wh  = dts + 64;
#define PS Cs

    int bl0 = b * L_SZ + c * QC;
    const float* zb = zxbcdt + (size_t)bl0 * D_IN_PROJ;

    if (tid < 64) {
        int t = tid;
        float draw = zb[(size_t)t * D_IN_PROJ + 2 * D_INNER + 2 * D_STATE + h];
        float dtv = draw + dt_bias[h];
        dtv = (dtv > 20.f) ? dtv : log1pf(expf(dtv));
        float A = -expf(A_log[h]);
        float cs = A * dtv;
#pragma unroll
        for (int off = 1; off < 64; off <<= 1) {
            float tmp = __shfl_up(cs, off);
            if (t >= off) cs += tmp;
        }
        float cs63 = __shfl(cs, 63);
        dts[t] = dtv;
        csh[t] = cs;
        wh[t] = __expf(cs63 - cs);
        Ebuf[(((size_t)(b * NHEADS + h) * NCH) + c) * QC + t] = __expf(cs);
    }

    int row16 = tid >> 4;
    int col4 = (tid & 15) * 4;
#pragma unroll
    for (int r = 0; r < 4; ++r) {
        int t = r * 16 + row16;
        int gl = c * QC + t;
        const float* prow = zb + (size_t)t * D_IN_PROJ;
        float4 Bv = conv4(prow, gl, D_INNER + D_INNER + col4, conv_w, conv_b);
        float4 Cv = conv4(prow, gl, D_INNER + D_INNER + D_STATE + col4, conv_w, conv_b);
        ushort4t bq = {f2bf(Bv.x), f2bf(Bv.y), f2bf(Bv.z), f2bf(Bv.w)};
        ushort4t cq = {f2bf(Cv.x), f2bf(Cv.y), f2bf(Cv.z), f2bf(Cv.w)};
        *(ushort4t*)&Bs[t * PB + col4] = bq;
        *(ushort4t*)&Cs[t * PB + col4] = cq;
    }
    __syncthreads();               // Bs/Cs/dts/wh visible

#pragma unroll
    for (int r = 0; r < 4; ++r) {
        int t = r * 16 + row16;
        int gl = c * QC + t;
        const float* prow = zb + (size_t)t * D_IN_PROJ;
        float4 xv = conv4(prow, gl, D_INNER + h * HEAD_DIM + col4, conv_w, conv_b);
        float d = dts[t], wt = wh[t];
        xv.x *= d; xv.y *= d; xv.z *= d; xv.w *= d;
        ushort4t xq = {f2bf(xv.x), f2bf(xv.y), f2bf(xv.z), f2bf(xv.w)};
        ushort4t bq = *(ushort4t*)&Bs[t * PB + col4];
#pragma unroll
        for (int q = 0; q < 4; ++q) {
            XDT[(col4 + q) * PB + t] = xq[q];
            BTw[(col4 + q) * PB + t] = f2bf(bf2f(bq[q]) * wt);
        }
    }
    __syncthreads();               // XDT/BTw visible

    int l = tid & 63, wv = tid >> 6;
    int wm = wv >> 1, wn = wv & 1;
    int fr = l & 15, fq = l >> 4;

    f32x4 g[2][2];
    {
#pragma unroll
        for (int i = 0; i < 2; ++i)
#pragma unroll
            for (int j = 0; j < 2; ++j) g[i][j] = (f32x4){0.f, 0.f, 0.f, 0.f};
#pragma unroll
        for (int kk = 0; kk < 2; ++kk) {
            short8t af[2], bb[2];
#pragma unroll
            for (int i = 0; i < 2; ++i)
                af[i] = *(const short8t*)&Cs[(wm * 32 + i * 16 + fr) * PB + kk * 32 + fq * 8];
#pragma unroll
            for (int j = 0; j < 2; ++j)
                bb[j] = *(const short8t*)&Bs[(wn * 32 + j * 16 + fr) * PB + kk * 32 + fq * 8];
#pragma unroll
            for (int i = 0; i < 2; ++i)
#pragma unroll
                for (int j = 0; j < 2; ++j)
                    g[i][j] = __builtin_amdgcn_mfma_f32_16x16x32_bf16(af[i], bb[j], g[i][j], 0, 0, 0);
        }
    }
    __syncthreads();               // Cs reads done -> safe to overwrite with P

    {
#pragma unroll
        for (int i = 0; i < 2; ++i)
#pragma unroll
            for (int j = 0; j < 2; ++j) {
                int s = wn * 32 + j * 16 + fr;
                float css = csh[s];
#pragma unroll
                for (int r = 0; r < 4; ++r) {
                    int t = wm * 32 + i * 16 + fq * 4 + r;
                    float v = (s <= t) ? g[i][j][r] * __expf(csh[t] - css) : 0.f;
                    PS[t * PB + s] = f2bf(v);
                }
            }
    }
    __syncthreads();               // P visible

    {   // Y = P·XD + D·x
        f32x4 yv[2][2];
#pragma unroll
        for (int i = 0; i < 2; ++i)
#pragma unroll
            for (int j = 0; j < 2; ++j) yv[i][j] = (f32x4){0.f, 0.f, 0.f, 0.f};
#pragma unroll
        for (int kk = 0; kk < 2; ++kk) {
            short8t af[2], bb[2];
#pragma unroll
            for (int i = 0; i < 2; ++i)
                af[i] = *(const short8t*)&PS[(wm * 32 + i * 16 + fr) * PB + kk * 32 + fq * 8];
#pragma unroll
            for (int j = 0; j < 2; ++j)
                bb[j] = *(const short8t*)&XDT[(wn * 32 + j * 16 + fr) * PB + kk * 32 + fq * 8];
#pragma unroll
            for (int i = 0; i < 2; ++i)
#pragma unroll
                for (int j = 0; j < 2; ++j)
                    yv[i][j] = __builtin_amdgcn_mfma_f32_16x16x32_bf16(af[i], bb[j], yv[i][j], 0, 0, 0);
        }
        float Dp = D_param[h];
#pragma unroll
        for (int i = 0; i < 2; ++i)
#pragma unroll
            for (int j = 0; j < 2; ++j) {
                int p = wn * 32 + j * 16 + fr;
#pragma unroll
                for (int r = 0; r < 4; ++r) {
                    int t = wm * 32 + i * 16 + fq * 4 + r;
                    float xval = bf2f(XDT[p * PB + t]);
                    float fct = Dp / dts[t];
                    y[(size_t)(bl0 + t) * D_INNER + h * HEAD_DIM + p] =
                        yv[i][j][r] + fct * xval;
                }
            }
    }

    {   // Z = XD^T·(w·B)
        f32x4 zv[2][2];
#pragma unroll
        for (int i = 0; i < 2; ++i)
#pragma unroll
            for (int j = 0; j < 2; ++j) zv[i][j] = (f32x4){0.f, 0.f, 0.f, 0.f};
#pragma unroll
        for (int kk = 0; kk < 2; ++kk) {
            short8t af[2], bb[2];
#pragma unroll
            for (int i = 0; i < 2; ++i)
                af[i] = *(const short8t*)&XDT[(wm * 32 + i * 16 + fr) * PB + kk * 32 + fq * 8];
#pragma unroll
            for (int j = 0; j < 2; ++j)
                bb[j] = *(const short8t*)&BTw[(wn * 32 + j * 16 + fr) * PB + kk * 32 + fq * 8];
#pragma unroll
            for (int i = 0; i < 2; ++i)
#pragma unroll
                for (int j = 0; j < 2; ++j)
                    zv[i][j] = __builtin_amdgcn_mfma_f32_16x16x32_bf16(af[i], bb[j], zv[i][j], 0, 0, 0);
        }
        float* Zr = Zbuf + (((size_t)(b * NHEADS + h) * NCH) + c) * (HEAD_DIM * D_STATE);
#pragma unroll
        for (int i = 0; i < 2; ++i)
#pragma unroll
            for (int j = 0; j < 2; ++j) {
                int n = wn * 32 + j * 16 + fr;
#pragma unroll
                for (int r = 0; r < 4; ++r) {
                    int p = wm * 32 + i * 16 + fq * 4 + r;
                    Zr[p * D_STATE + n] = zv[i][j][r];
                }
            }
    }
#undef PS
}

__device__ __forceinline__ void passC_body(int blk, int tid, char* smem,
        const float* __restrict__ zxbcdt, const float* __restrict__ conv_w,
        const float* __restrict__ conv_b, const float* __restrict__ Zbuf,
        const float* __restrict__ Ebuf, float* __restrict__ y) {
    int h = blk & 15;
    int q = blk >> 4;              // 0..13
    int c = 1 + (q % 7);
    int b = q / 7;

    unsigned short* Cs = (unsigned short*)smem;   // [64][72]
    unsigned short* S  = Cs + 64 * PB;
    float* Eh = (float*)(smem + 2 * 64 * PB * 2);

    int bl0 = b * L_SZ + c * QC;
    const float* zb = zxbcdt + (size_t)bl0 * D_IN_PROJ;
    const float* Zb = Zbuf + ((size_t)(b * NHEADS + h) * NCH) * (HEAD_DIM * D_STATE);
    const float* Eb = Ebuf + ((size_t)(b * NHEADS + h) * NCH) * QC;

    {
        int p = tid >> 2, nq = (tid & 3) * 16;
        float S16[16];
#pragma unroll
        for (int qq = 0; qq < 16; ++qq) S16[qq] = 0.f;
        float wgt = 1.f;
        for (int j = c - 1; j >= 0; --j) {
            const float* Zj = Zb + (size_t)j * (HEAD_DIM * D_STATE) + p * D_STATE + nq;
#pragma unroll
            for (int q4 = 0; q4 < 4; ++q4) {
                float4 z = *(const float4*)(Zj + q4 * 4);
                S16[q4 * 4 + 0] += wgt * z.x;
                S16[q4 * 4 + 1] += wgt * z.y;
                S16[q4 * 4 + 2] += wgt * z.z;
                S16[q4 * 4 + 3] += wgt * z.w;
            }
            wgt *= Eb[(size_t)j * QC + 63];
        }
#pragma unroll
        for (int q4 = 0; q4 < 4; ++q4) {
            ushort4t s4 = {f2bf(S16[q4 * 4 + 0]), f2bf(S16[q4 * 4 + 1]),
                           f2bf(S16[q4 * 4 + 2]), f2bf(S16[q4 * 4 + 3])};
            *(ushort4t*)&S[p * PB + nq + q4 * 4] = s4;
        }
    }

    int row16 = tid >> 4, col4 = (tid & 15) * 4;
#pragma unroll
    for (int r = 0; r < 4; ++r) {
        int t = r * 16 + row16;
        int gl = c * QC + t;
        float4 Cv = conv4(zb + (size_t)t * D_IN_PROJ, gl,
                          D_INNER + D_INNER + D_STATE + col4, conv_w, conv_b);
        ushort4t cq = {f2bf(Cv.x), f2bf(Cv.y), f2bf(Cv.z), f2bf(Cv.w)};
        *(ushort4t*)&Cs[t * PB + col4] = cq;
    }
    if (tid < 64)
        Eh[tid] = Ebuf[(((size_t)(b * NHEADS + h) * NCH) + c) * QC + tid];
    __syncthreads();

    int l = tid & 63, wv = tid >> 6;
    int wm = wv >> 1, wn = wv & 1;
    int fr = l & 15, fq = l >> 4;
    f32x4 acc[2][2];
#pragma unroll
    for (int i = 0; i < 2; ++i)
#pragma unroll
        for (int j = 0; j < 2; ++j) acc[i][j] = (f32x4){0.f, 0.f, 0.f, 0.f};
#pragma unroll
    for (int kk = 0; kk < 2; ++kk) {
        short8t af[2], bb[2];
#pragma unroll
        for (int i = 0; i < 2; ++i)
            af[i] = *(const short8t*)&Cs[(wm * 32 + i * 16 + fr) * PB + kk * 32 + fq * 8];
#pragma unroll
        for (int j = 0; j < 2; ++j)
            bb[j] = *(const short8t*)&S[(wn * 32 + j * 16 + fr) * PB + kk * 32 + fq * 8];
#pragma unroll
        for (int i = 0; i < 2; ++i)
#pragma unroll
            for (int j = 0; j < 2; ++j)
                acc[i][j] = __builtin_amdgcn_mfma_f32_16x16x32_bf16(af[i], bb[j], acc[i][j], 0, 0, 0);
    }
#pragma unroll
    for (int i = 0; i < 2; ++i)
#pragma unroll
        for (int j = 0; j < 2; ++j) {
            int p = wn * 32 + j * 16 + fr;
#pragma unroll
            for (int r = 0; r < 4; ++r) {
                int t = wm * 32 + i * 16 + fq * 4 + r;
                float* yp = y + (size_t)(bl0 + t) * D_INNER + h * HEAD_DIM + p;
                *yp += Eh[t] * acc[i][j][r];
            }
        }
}

__device__ __forceinline__ void norm_body(int blk, int tid, char* smem,
        const float* __restrict__ zxbcdt, const float* __restrict__ y,
        const float* __restrict__ rms_w, unsigned short* __restrict__ yn_bf) {
    float* red = (float*)smem;       // [4]
    float* ssc = red + 4;
    for (int rr = 0; rr < 4; ++rr) {
        int bl = blk * 4 + rr;
        float vals[4];
        float sumsq = 0.f;
#pragma unroll
        for (int i = 0; i < 4; ++i) {
            int col = tid + i * 256;
            float yv = y[(size_t)bl * D_INNER + col];
            float z = zxbcdt[(size_t)bl * D_IN_PROJ + col];
            float yz = yv * (z / (1.f + __expf(-z)));
            vals[i] = yz;
            sumsq += yz * yz;
        }
#pragma unroll
        for (int off = 32; off; off >>= 1) sumsq += __shfl_xor(sumsq, off);
        int wave = tid >> 6, lane = tid & 63;
        if (lane == 0) red[wave] = sumsq;
        __syncthreads();
        if (tid == 0) {
            float t = red[0] + red[1] + red[2] + red[3];
            ssc[0] = rsqrtf(t / (float)D_INNER + RMS_EPS);
        }
        __syncthreads();
        float sc = ssc[0];
#pragma unroll
        for (int i = 0; i < 4; ++i) {
            int col = tid + i * 256;
            yn_bf[(size_t)bl * D_INNER + col] = f2bf(vals[i] * sc * rms_w[col]);
        }
        __syncthreads();             // guard red/ssc reuse next row
    }
}

__device__ __forceinline__ void gemm2_body(int blk, int tid, char* smem,
        const unsigned short* __restrict__ A, const unsigned short* __restrict__ Bt,
        float* __restrict__ out) {
    const int K = D_INNER, N = D_MODEL;
    int w = tid >> 6, l = tid & 63;
    int n0 = (blk & 7) * 64, m0 = (blk >> 3) * 32;
    int wm = w >> 1, wn = w & 1;

    f32x4 acc[2];
    acc[0] = (f32x4){0.f, 0.f, 0.f, 0.f};
    acc[1] = (f32x4){0.f, 0.f, 0.f, 0.f};

    auto stageA = [&](int k0, char* dst) {
        int row = w * 8 + (l >> 3);
        int scb = ((l & 7) << 4) ^ ((row & 7) << 4);
        gload_lds16(A + (size_t)(m0 + row) * K + k0 + (scb >> 1), dst + w * 1024);
    };
    auto stageB = [&](int k0, char* dst) {
#pragma unroll
        for (int p = 0; p < 2; ++p) {
            int c = w * 2 + p;
            int row = c * 8 + (l >> 3);
            int scb = ((l & 7) << 4) ^ ((row & 7) << 4);
            gload_lds16(Bt + (size_t)(n0 + row) * K + k0 + (scb >> 1), dst + c * 1024);
        }
    };

    const int nkt = K / 64;   // 16
    stageA(0, smem); stageB(0, smem + 4096);
    stageA(64, smem + 12288); stageB(64, smem + 12288 + 4096);

    for (int kt = 0; kt < nkt; ++kt) {
        if (kt + 2 < nkt) {
            char* d = smem + ((kt + 2) % 3) * 12288;
            stageA((kt + 2) * 64, d);
            stageB((kt + 2) * 64, d + 4096);
        }
        int inflight = nkt - 1 - kt;
        if (inflight >= 2)      asm volatile("s_waitcnt vmcnt(6)" ::: "memory");
        else if (inflight == 1) asm volatile("s_waitcnt vmcnt(3)" ::: "memory");
        else                    asm volatile("s_waitcnt vmcnt(0)" ::: "memory");
        __builtin_amdgcn_s_barrier();

        const char* Ab = smem + (kt % 3) * 12288;
        const char* Bb = Ab + 4096;
#pragma unroll
        for (int kk = 0; kk < 2; ++kk) {
            short8t af;
            {
                int r = wm * 16 + (l & 15);
                int cb = (kk * 64 + (l >> 4) * 16) ^ ((r & 7) << 4);
                af = *(const short8t*)(Ab + r * 128 + cb);
            }
#pragma unroll
            for (int j = 0; j < 2; ++j) {
                int r = wn * 32 + j * 16 + (l & 15);
                int cb = (kk * 64 + (l >> 4) * 16) ^ ((r & 7) << 4);
                short8t bfv = *(const short8t*)(Bb + r * 128 + cb);
                acc[j] = __builtin_amdgcn_mfma_f32_16x16x32_bf16(af, bfv, acc[j], 0, 0, 0);
            }
        }
        __builtin_amdgcn_s_barrier();
    }

#pragma unroll
    for (int j = 0; j < 2; ++j) {
        int col = n0 + wn * 32 + j * 16 + (l & 15);
        int rowb = m0 + wm * 16 + (l >> 4) * 4;
#pragma unroll
        for (int r = 0; r < 4; ++r)
            out[(size_t)(rowb + r) * N + col] = acc[j][r];
    }
}

// ---------------- mega kernel: passA -> passC -> norm -> out_proj ----------------
__global__ __launch_bounds__(256) void ssd_mega(const float* __restrict__ zxbcdt,
                                                const float* __restrict__ conv_w,
                                                const float* __restrict__ conv_b,
                                                const float* __restrict__ dt_bias,
                                                const float* __restrict__ A_log,
                                                const float* __restrict__ D_param,
                                                const float* __restrict__ rms_w,
                                                const unsigned short* __restrict__ Wt2,
                                                float* __restrict__ y,
                                                float* __restrict__ Zbuf,
                                                float* __restrict__ Ebuf,
                                                unsigned short* __restrict__ yn_bf,
                                                float* __restrict__ out,
                                                unsigned* __restrict__ cnt) {
    __shared__ __align__(16) char smem[37632];
    int blk = blockIdx.x, tid = threadIdx.x;

    passA_body(blk, tid, smem, zxbcdt, conv_w, conv_b, dt_bias, A_log, D_param,
               y, Zbuf, Ebuf);
    grid_barrier(cnt, 0);

    if (blk < 224)
        passC_body(blk, tid, smem, zxbcdt, conv_w, conv_b, Zbuf, Ebuf, y);
    grid_barrier(cnt, 1);

    norm_body(blk, tid, smem, zxbcdt, y, rms_w, yn_bf);
    grid_barrier(cnt, 2);

    gemm2_body(blk, tid, smem, yn_bf, Wt2, out);
}

// ---------------- launch ----------------
extern "C" void kernel_launch(void* const* d_in, const int* in_sizes, int n_in,
                              void* d_out, int out_size, void* d_ws, size_t ws_size,
                              hipStream_t stream) {
    const float* u       = (const float*)d_in[0];
    const float* W_in    = (const float*)d_in[1];
    const float* conv_w  = (const float*)d_in[2];
    const float* conv_b  = (const float*)d_in[3];
    const float* dt_bias = (const float*)d_in[4];
    const float* A_log   = (const float*)d_in[5];
    const float* D_param = (const float*)d_in[6];
    const float* rms_w   = (const float*)d_in[7];
    const float* W_out   = (const float*)d_in[8];
    float* out = (float*)d_out;

    float* ws = (float*)d_ws;
    float* zxbcdt = ws;                                    // [1024][2192] f32
    float* y      = zxbcdt + (size_t)BL * D_IN_PROJ;       // [1024][1024] f32
    float* Zbuf   = y + (size_t)BL * D_INNER;              // [32][8][64][64] f32
    float* Ebuf   = Zbuf + (size_t)32 * NCH * 4096;        // [32][8][64] f32
    unsigned short* u_bf  = (unsigned short*)(Ebuf + 32 * NCH * QC);   // [1024][512]
    unsigned short* Wt1   = u_bf + (size_t)BL * D_MODEL;               // [2304][512]
    unsigned short* Wt2   = Wt1 + (size_t)NPAD1 * D_MODEL;             // [512][1024]
    unsigned short* yn_bf = Wt2 + (size_t)D_MODEL * D_INNER;           // [1024][1024]
    unsigned* cnt = (unsigned*)(yn_bf + (size_t)BL * D_INNER);         // [8]

    // 0) convert/transpose weights + u to bf16; zero barrier counters
    prep_kernel<<<672, 256, 0, stream>>>(W_in, W_out, u, Wt1, Wt2, u_bf, cnt);

    // 1) in_proj: zxbcdt = u @ W_in
    gemm_mfma64<<<dim3(NPAD1 / 64, BL / 64), 256, 0, stream>>>(
        u_bf, Wt1, zxbcdt, D_IN_PROJ, D_MODEL);

    // 2) SSD + gate/RMSNorm + out_proj in one persistent kernel (grid barriers)
    ssd_mega<<<NBLK, 256, 0, stream>>>(
        zxbcdt, conv_w, conv_b, dt_bias, A_log, D_param, rms_w, Wt2,
        y, Zbuf, Ebuf, yn_bf, out, cnt);
}

// Round 10
// 46.969 us; speedup vs baseline: 2.1909x; 2.1909x over previous
//
#include <hip/hip_runtime.h>
#include <hip/hip_bf16.h>

// ---------------- constants ----------------
#define B_SZ 2
#define L_SZ 512
#define D_MODEL 512
#define D_INNER 1024
#define HEAD_DIM 64
#define NHEADS 16
#define D_STATE 64
#define D_CONV 3
#define CONV_DIM 1152            // D_INNER + 2*D_STATE
#define D_IN_PROJ 2192           // 2*D_INNER + 2*D_STATE + NHEADS
#define BL (B_SZ * L_SZ)         // 1024
#define RMS_EPS 1e-5f
#define QC 64                    // SSD chunk length
#define NCH 8                    // chunks per batch (L_SZ/QC)
#define NPAD1 2304               // W_in^T padded rows (36*64)
#define PB 72                    // bf16 LDS pitch (144B rows: frag reads 2-way = free)

typedef __attribute__((ext_vector_type(8))) short short8t;
typedef __attribute__((ext_vector_type(8))) unsigned short ushort8t;
typedef __attribute__((ext_vector_type(4))) unsigned short ushort4t;
typedef __attribute__((ext_vector_type(4))) float f32x4;

__device__ __forceinline__ unsigned short f2bf(float f) {
    unsigned u = __float_as_uint(f);
    u += 0x7fff + ((u >> 16) & 1);          // round-to-nearest-even
    return (unsigned short)(u >> 16);
}
__device__ __forceinline__ float bf2f(unsigned short u) {
    return __uint_as_float(((unsigned)u) << 16);
}

__device__ __forceinline__ void gload_lds16(const void* g, void* lds) {
    __builtin_amdgcn_global_load_lds(
        (const __attribute__((address_space(1))) unsigned int*)g,
        (__attribute__((address_space(3))) unsigned int*)lds, 16, 0, 0);
}

// ---------------- prep: W_in -> Wt1[2304][512] bf16, W_out -> Wt2[512][1024] bf16, u -> bf16
__device__ __forceinline__ void transpose_tile_bf16(const float* __restrict__ src,
                                                    unsigned short* __restrict__ dst,
                                                    int K, int Nin, int tile, int ntn) {
    __shared__ float T[64][65];
    int tid = threadIdx.x;
    int nt = tile % ntn, kt = tile / ntn;
    int n0 = nt * 64, k0 = kt * 64;
#pragma unroll
    for (int rr = 0; rr < 4; ++rr) {
        int k = k0 + (tid >> 4) + rr * 16;
        int nn = (tid & 15) * 4;
#pragma unroll
        for (int q = 0; q < 4; ++q) {
            int n = n0 + nn + q;
            T[(tid >> 4) + rr * 16][nn + q] = (n < Nin) ? src[(size_t)k * Nin + n] : 0.f;
        }
    }
    __syncthreads();
    int nn2 = tid >> 2, kc = tid & 3;
    unsigned short ov[16];
#pragma unroll
    for (int j = 0; j < 16; ++j) ov[j] = f2bf(T[kc * 16 + j][nn2]);
    unsigned short* p = dst + (size_t)(n0 + nn2) * K + k0 + kc * 16;
    *(ushort8t*)p = *(ushort8t*)&ov[0];
    *(ushort8t*)(p + 8) = *(ushort8t*)&ov[8];
}

__global__ __launch_bounds__(256) void prep_kernel(const float* __restrict__ W_in,
                                                   const float* __restrict__ W_out,
                                                   const float* __restrict__ u,
                                                   unsigned short* __restrict__ Wt1,
                                                   unsigned short* __restrict__ Wt2,
                                                   unsigned short* __restrict__ u_bf) {
    int bid = blockIdx.x;
    if (bid < 288) {
        transpose_tile_bf16(W_in, Wt1, D_MODEL, D_IN_PROJ, bid, 36);
    } else if (bid < 416) {
        transpose_tile_bf16(W_out, Wt2, D_INNER, D_MODEL, bid - 288, 8);
    } else {
        int i = ((bid - 416) * 256 + threadIdx.x) * 8;
        float4 v0 = *(const float4*)(u + i);
        float4 v1 = *(const float4*)(u + i + 4);
        unsigned short ov[8] = {f2bf(v0.x), f2bf(v0.y), f2bf(v0.z), f2bf(v0.w),
                                f2bf(v1.x), f2bf(v1.y), f2bf(v1.z), f2bf(v1.w)};
        *(ushort8t*)(u_bf + i) = *(ushort8t*)&ov[0];
    }
}

// ---------------- in_proj GEMM 64x64 + split epilogue ----------------
// z cols -> f32 zxbcdt; xBC cols -> bf16 xbc_bf (compact); dt cols -> f32 dtb.
__global__ __launch_bounds__(256) void gemm_in(const unsigned short* __restrict__ A,
                                               const unsigned short* __restrict__ Bt,
                                               float* __restrict__ C,
                                               unsigned short* __restrict__ xbc,
                                               float* __restrict__ dtb) {
    const int K = D_MODEL;
    __shared__ char sm[49152];          // 3 buf x (A:8192 | B:8192)
    int tid = threadIdx.x;
    int w = tid >> 6, l = tid & 63;
    int m0 = blockIdx.y * 64, n0 = blockIdx.x * 64;
    int wm = w >> 1, wn = w & 1;

    f32x4 acc[2][2];
#pragma unroll
    for (int i = 0; i < 2; ++i)
#pragma unroll
        for (int j = 0; j < 2; ++j) acc[i][j] = (f32x4){0.f, 0.f, 0.f, 0.f};

    auto stage = [&](const unsigned short* src, int row0, int k0, char* dst) {
#pragma unroll
        for (int p = 0; p < 2; ++p) {
            int c = w * 2 + p;
            int row = c * 8 + (l >> 3);
            int scb = ((l & 7) << 4) ^ ((row & 7) << 4);
            gload_lds16(src + (size_t)(row0 + row) * K + k0 + (scb >> 1), dst + c * 1024);
        }
    };

    const int nkt = K / 64;   // 8
    stage(A, m0, 0, sm);
    stage(Bt, n0, 0, sm + 8192);
    stage(A, m0, 64, sm + 16384);
    stage(Bt, n0, 64, sm + 16384 + 8192);

    for (int kt = 0; kt < nkt; ++kt) {
        if (kt + 2 < nkt) {
            char* d = sm + ((kt + 2) % 3) * 16384;
            stage(A, m0, (kt + 2) * 64, d);
            stage(Bt, n0, (kt + 2) * 64, d + 8192);
        }
        int inflight = nkt - 1 - kt;
        if (inflight >= 2)      asm volatile("s_waitcnt vmcnt(8)" ::: "memory");
        else if (inflight == 1) asm volatile("s_waitcnt vmcnt(4)" ::: "memory");
        else                    asm volatile("s_waitcnt vmcnt(0)" ::: "memory");
        __builtin_amdgcn_s_barrier();

        const char* Ab = sm + (kt % 3) * 16384;
        const char* Bb = Ab + 8192;
#pragma unroll
        for (int kk = 0; kk < 2; ++kk) {
            short8t af[2], bf[2];
#pragma unroll
            for (int i = 0; i < 2; ++i) {
                int r = wm * 32 + i * 16 + (l & 15);
                int cb = (kk * 64 + (l >> 4) * 16) ^ ((r & 7) << 4);
                af[i] = *(const short8t*)(Ab + r * 128 + cb);
            }
#pragma unroll
            for (int j = 0; j < 2; ++j) {
                int r = wn * 32 + j * 16 + (l & 15);
                int cb = (kk * 64 + (l >> 4) * 16) ^ ((r & 7) << 4);
                bf[j] = *(const short8t*)(Bb + r * 128 + cb);
            }
#pragma unroll
            for (int i = 0; i < 2; ++i)
#pragma unroll
                for (int j = 0; j < 2; ++j)
                    acc[i][j] = __builtin_amdgcn_mfma_f32_16x16x32_bf16(af[i], bf[j], acc[i][j], 0, 0, 0);
        }
        __builtin_amdgcn_s_barrier();
    }

#pragma unroll
    for (int i = 0; i < 2; ++i)
#pragma unroll
        for (int j = 0; j < 2; ++j) {
            int row = m0 + wm * 32 + i * 16 + (l >> 4) * 4;
            int col = n0 + wn * 32 + j * 16 + (l & 15);
#pragma unroll
            for (int r = 0; r < 4; ++r) {
                float v = acc[i][j][r];
                int rr = row + r;
                if (col < D_INNER) {
                    C[(size_t)rr * D_IN_PROJ + col] = v;            // z (f32 for gate)
                } else if (col < D_INNER + CONV_DIM) {
                    xbc[(size_t)rr * CONV_DIM + (col - D_INNER)] = f2bf(v);
                } else if (col < D_IN_PROJ) {
                    dtb[(size_t)rr * 16 + (col - D_INNER - CONV_DIM)] = v;
                }
            }
        }
}

// ---------------- out_proj GEMM 32x64 (256 blocks) ----------------
__global__ __launch_bounds__(256) void gemm_mfma32(const unsigned short* __restrict__ A,
                                                   const unsigned short* __restrict__ Bt,
                                                   float* __restrict__ C,
                                                   int N, int K) {
    __shared__ char sm[36864];          // 3 buf x (A:4096 | B:8192)
    int tid = threadIdx.x;
    int w = tid >> 6, l = tid & 63;
    int m0 = blockIdx.y * 32, n0 = blockIdx.x * 64;
    int wm = w >> 1, wn = w & 1;

    f32x4 acc[2];
    acc[0] = (f32x4){0.f, 0.f, 0.f, 0.f};
    acc[1] = (f32x4){0.f, 0.f, 0.f, 0.f};

    auto stageA = [&](int k0, char* dst) {
        int row = w * 8 + (l >> 3);
        int scb = ((l & 7) << 4) ^ ((row & 7) << 4);
        gload_lds16(A + (size_t)(m0 + row) * K + k0 + (scb >> 1), dst + w * 1024);
    };
    auto stageB = [&](int k0, char* dst) {
#pragma unroll
        for (int p = 0; p < 2; ++p) {
            int c = w * 2 + p;
            int row = c * 8 + (l >> 3);
            int scb = ((l & 7) << 4) ^ ((row & 7) << 4);
            gload_lds16(Bt + (size_t)(n0 + row) * K + k0 + (scb >> 1), dst + c * 1024);
        }
    };

    int nkt = K / 64;
    stageA(0, sm); stageB(0, sm + 4096);
    stageA(64, sm + 12288); stageB(64, sm + 12288 + 4096);

    for (int kt = 0; kt < nkt; ++kt) {
        if (kt + 2 < nkt) {
            char* d = sm + ((kt + 2) % 3) * 12288;
            stageA((kt + 2) * 64, d);
            stageB((kt + 2) * 64, d + 4096);
        }
        int inflight = nkt - 1 - kt;
        if (inflight >= 2)      asm volatile("s_waitcnt vmcnt(6)" ::: "memory");
        else if (inflight == 1) asm volatile("s_waitcnt vmcnt(3)" ::: "memory");
        else                    asm volatile("s_waitcnt vmcnt(0)" ::: "memory");
        __builtin_amdgcn_s_barrier();

        const char* Ab = sm + (kt % 3) * 12288;
        const char* Bb = Ab + 4096;
#pragma unroll
        for (int kk = 0; kk < 2; ++kk) {
            short8t af;
            {
                int r = wm * 16 + (l & 15);
                int cb = (kk * 64 + (l >> 4) * 16) ^ ((r & 7) << 4);
                af = *(const short8t*)(Ab + r * 128 + cb);
            }
#pragma unroll
            for (int j = 0; j < 2; ++j) {
                int r = wn * 32 + j * 16 + (l & 15);
                int cb = (kk * 64 + (l >> 4) * 16) ^ ((r & 7) << 4);
                short8t bfv = *(const short8t*)(Bb + r * 128 + cb);
                acc[j] = __builtin_amdgcn_mfma_f32_16x16x32_bf16(af, bfv, acc[j], 0, 0, 0);
            }
        }
        __builtin_amdgcn_s_barrier();
    }

#pragma unroll
    for (int j = 0; j < 2; ++j) {
        int col = n0 + wn * 32 + j * 16 + (l & 15);
        int rowb = m0 + wm * 16 + (l >> 4) * 4;
#pragma unroll
        for (int r = 0; r < 4; ++r)
            C[(size_t)(rowb + r) * N + col] = acc[j][r];
    }
}

// conv+SiLU of 4 channels from compact bf16 xbc buffer; gl = seq position
__device__ __forceinline__ float4 conv4b(const unsigned short* __restrict__ xrow,
                                         int gl, int ch,
                                         const float* __restrict__ conv_w,
                                         const float* __restrict__ conv_b) {
    ushort4t u2 = *(const ushort4t*)(xrow + ch);
    ushort4t u1 = {0, 0, 0, 0}, u0 = {0, 0, 0, 0};
    if (gl >= 1) u1 = *(const ushort4t*)(xrow + ch - CONV_DIM);
    if (gl >= 2) u0 = *(const ushort4t*)(xrow + ch - 2 * CONV_DIM);
    float4 o;
    float a;
    a = conv_b[ch+0] + conv_w[(ch+0)*3]*bf2f(u0[0]) + conv_w[(ch+0)*3+1]*bf2f(u1[0]) + conv_w[(ch+0)*3+2]*bf2f(u2[0]);
    o.x = a / (1.f + __expf(-a));
    a = conv_b[ch+1] + conv_w[(ch+1)*3]*bf2f(u0[1]) + conv_w[(ch+1)*3+1]*bf2f(u1[1]) + conv_w[(ch+1)*3+2]*bf2f(u2[1]);
    o.y = a / (1.f + __expf(-a));
    a = conv_b[ch+2] + conv_w[(ch+2)*3]*bf2f(u0[2]) + conv_w[(ch+2)*3+1]*bf2f(u1[2]) + conv_w[(ch+2)*3+2]*bf2f(u2[2]);
    o.z = a / (1.f + __expf(-a));
    a = conv_b[ch+3] + conv_w[(ch+3)*3]*bf2f(u0[3]) + conv_w[(ch+3)*3+1]*bf2f(u1[3]) + conv_w[(ch+3)*3+2]*bf2f(u2[3]);
    o.w = a / (1.f + __expf(-a));
    return o;
}

// ---------------- SSD pass A (conv from compact bf16; MFMA; slim LDS) ----------------
__global__ __launch_bounds__(256) void ssd_passA(const unsigned short* __restrict__ xbc,
                                                 const float* __restrict__ dtb,
                                                 const float* __restrict__ conv_w,
                                                 const float* __restrict__ conv_b,
                                                 const float* __restrict__ dt_bias,
                                                 const float* __restrict__ A_log,
                                                 const float* __restrict__ D_param,
                                                 float* __restrict__ y,
                                                 float* __restrict__ Zbuf,
                                                 float* __restrict__ Ebuf) {
    int blk = blockIdx.x;          // b*128 + c*16 + h
    int h = blk & 15;
    int c = (blk >> 4) & 7;
    int b = blk >> 7;
    int tid = threadIdx.x;

    __shared__ __align__(16) unsigned short Cs_bf[QC][PB];   // C[t][n]; reused as P[t][s]
    __shared__ __align__(16) unsigned short Bs_bf[QC][PB];   // B[s][n]
    __shared__ __align__(16) unsigned short XDT_bf[QC][PB];  // XD^T[p][t]
    __shared__ __align__(16) unsigned short BTw_bf[QC][PB];  // (w·B)^T[n][t]
    __shared__ float csh[QC], dts[QC], wh[QC];
#define PS_bf Cs_bf

    int bl0 = b * L_SZ + c * QC;

    // dt, cumsum, decays (wave 0) — dtb rows are 64B stride (compact)
    if (tid < 64) {
        int t = tid;
        float draw = dtb[(size_t)(bl0 + t) * 16 + h];
        float dtv = draw + dt_bias[h];
        dtv = (dtv > 20.f) ? dtv : log1pf(expf(dtv));
        float A = -expf(A_log[h]);
        float cs = A * dtv;
#pragma unroll
        for (int off = 1; off < 64; off <<= 1) {
            float tmp = __shfl_up(cs, off);
            if (t >= off) cs += tmp;
        }
        float cs63 = __shfl(cs, 63);
        dts[t] = dtv;
        csh[t] = cs;
        wh[t] = __expf(cs63 - cs);
        Ebuf[(((size_t)(b * NHEADS + h) * NCH) + c) * QC + t] = __expf(cs);
    }

    int row16 = tid >> 4;
    int col4 = (tid & 15) * 4;
#pragma unroll
    for (int r = 0; r < 4; ++r) {
        int t = r * 16 + row16;
        int gl = c * QC + t;
        const unsigned short* xrow = xbc + (size_t)(bl0 + t) * CONV_DIM;
        float4 Bv = conv4b(xrow, gl, D_INNER + col4, conv_w, conv_b);
        float4 Cv = conv4b(xrow, gl, D_INNER + D_STATE + col4, conv_w, conv_b);
        ushort4t bq = {f2bf(Bv.x), f2bf(Bv.y), f2bf(Bv.z), f2bf(Bv.w)};
        ushort4t cq = {f2bf(Cv.x), f2bf(Cv.y), f2bf(Cv.z), f2bf(Cv.w)};
        *(ushort4t*)&Bs_bf[t][col4] = bq;
        *(ushort4t*)&Cs_bf[t][col4] = cq;
    }
    __syncthreads();               // sync1: Bs/Cs/dts/wh visible

#pragma unroll
    for (int r = 0; r < 4; ++r) {
        int t = r * 16 + row16;
        int gl = c * QC + t;
        const unsigned short* xrow = xbc + (size_t)(bl0 + t) * CONV_DIM;
        float4 xv = conv4b(xrow, gl, h * HEAD_DIM + col4, conv_w, conv_b);
        float d = dts[t], wt = wh[t];
        xv.x *= d; xv.y *= d; xv.z *= d; xv.w *= d;
        ushort4t xq = {f2bf(xv.x), f2bf(xv.y), f2bf(xv.z), f2bf(xv.w)};
        ushort4t bq = *(ushort4t*)&Bs_bf[t][col4];
#pragma unroll
        for (int q = 0; q < 4; ++q) {
            XDT_bf[col4 + q][t] = xq[q];
            BTw_bf[col4 + q][t] = f2bf(bf2f(bq[q]) * wt);
        }
    }
    __syncthreads();               // sync2: XDT/BTw visible

    int l = tid & 63, wv = tid >> 6;
    int wm = wv >> 1, wn = wv & 1;
    int fr = l & 15, fq = l >> 4;

    f32x4 g[2][2];
    {   // G = C·B^T via MFMA
#pragma unroll
        for (int i = 0; i < 2; ++i)
#pragma unroll
            for (int j = 0; j < 2; ++j) g[i][j] = (f32x4){0.f, 0.f, 0.f, 0.f};
#pragma unroll
        for (int kk = 0; kk < 2; ++kk) {
            short8t af[2], bb[2];
#pragma unroll
            for (int i = 0; i < 2; ++i)
                af[i] = *(const short8t*)&Cs_bf[wm * 32 + i * 16 + fr][kk * 32 + fq * 8];
#pragma unroll
            for (int j = 0; j < 2; ++j)
                bb[j] = *(const short8t*)&Bs_bf[wn * 32 + j * 16 + fr][kk * 32 + fq * 8];
#pragma unroll
            for (int i = 0; i < 2; ++i)
#pragma unroll
                for (int j = 0; j < 2; ++j)
                    g[i][j] = __builtin_amdgcn_mfma_f32_16x16x32_bf16(af[i], bb[j], g[i][j], 0, 0, 0);
        }
    }
    __syncthreads();               // sync3: Cs reads done -> safe to overwrite with P

    {   // mask+decay -> P (into Cs region)
#pragma unroll
        for (int i = 0; i < 2; ++i)
#pragma unroll
            for (int j = 0; j < 2; ++j) {
                int s = wn * 32 + j * 16 + fr;
                float css = csh[s];
#pragma unroll
                for (int r = 0; r < 4; ++r) {
                    int t = wm * 32 + i * 16 + fq * 4 + r;
                    float v = (s <= t) ? g[i][j][r] * __expf(csh[t] - css) : 0.f;
                    PS_bf[t][s] = f2bf(v);
                }
            }
    }
    __syncthreads();               // sync4: P visible

    {   // Y = P·XD via MFMA; epilogue + D·x
        f32x4 yv[2][2];
#pragma unroll
        for (int i = 0; i < 2; ++i)
#pragma unroll
            for (int j = 0; j < 2; ++j) yv[i][j] = (f32x4){0.f, 0.f, 0.f, 0.f};
#pragma unroll
        for (int kk = 0; kk < 2; ++kk) {
            short8t af[2], bb[2];
#pragma unroll
            for (int i = 0; i < 2; ++i)
                af[i] = *(const short8t*)&PS_bf[wm * 32 + i * 16 + fr][kk * 32 + fq * 8];
#pragma unroll
            for (int j = 0; j < 2; ++j)
                bb[j] = *(const short8t*)&XDT_bf[wn * 32 + j * 16 + fr][kk * 32 + fq * 8];
#pragma unroll
            for (int i = 0; i < 2; ++i)
#pragma unroll
                for (int j = 0; j < 2; ++j)
                    yv[i][j] = __builtin_amdgcn_mfma_f32_16x16x32_bf16(af[i], bb[j], yv[i][j], 0, 0, 0);
        }
        float Dp = D_param[h];
#pragma unroll
        for (int i = 0; i < 2; ++i)
#pragma unroll
            for (int j = 0; j < 2; ++j) {
                int p = wn * 32 + j * 16 + fr;
#pragma unroll
                for (int r = 0; r < 4; ++r) {
                    int t = wm * 32 + i * 16 + fq * 4 + r;
                    float xval = bf2f(XDT_bf[p][t]);
                    float fct = Dp / dts[t];
                    y[(size_t)(bl0 + t) * D_INNER + h * HEAD_DIM + p] =
                        yv[i][j][r] + fct * xval;
                }
            }
    }

    {   // Z = XD^T·(w·B) via MFMA -> Zbuf
        f32x4 zv[2][2];
#pragma unroll
        for (int i = 0; i < 2; ++i)
#pragma unroll
            for (int j = 0; j < 2; ++j) zv[i][j] = (f32x4){0.f, 0.f, 0.f, 0.f};
#pragma unroll
        for (int kk = 0; kk < 2; ++kk) {
            short8t af[2], bb[2];
#pragma unroll
            for (int i = 0; i < 2; ++i)
                af[i] = *(const short8t*)&XDT_bf[wm * 32 + i * 16 + fr][kk * 32 + fq * 8];
#pragma unroll
            for (int j = 0; j < 2; ++j)
                bb[j] = *(const short8t*)&BTw_bf[wn * 32 + j * 16 + fr][kk * 32 + fq * 8];
#pragma unroll
            for (int i = 0; i < 2; ++i)
#pragma unroll
                for (int j = 0; j < 2; ++j)
                    zv[i][j] = __builtin_amdgcn_mfma_f32_16x16x32_bf16(af[i], bb[j], zv[i][j], 0, 0, 0);
        }
        float* Zr = Zbuf + (((size_t)(b * NHEADS + h) * NCH) + c) * (HEAD_DIM * D_STATE);
#pragma unroll
        for (int i = 0; i < 2; ++i)
#pragma unroll
            for (int j = 0; j < 2; ++j) {
                int n = wn * 32 + j * 16 + fr;
#pragma unroll
                for (int r = 0; r < 4; ++r) {
                    int p = wm * 32 + i * 16 + fq * 4 + r;
                    Zr[p * D_STATE + n] = zv[i][j][r];
                }
            }
    }
#undef PS_bf
}

// ---------------- SSD pass C (passB folded; 224 blocks, c>=1 only) ----------------
__global__ __launch_bounds__(256) void ssd_passC(const unsigned short* __restrict__ xbc,
                                                 const float* __restrict__ conv_w,
                                                 const float* __restrict__ conv_b,
                                                 const float* __restrict__ Zbuf,
                                                 const float* __restrict__ Ebuf,
                                                 float* __restrict__ y) {
    int blk = blockIdx.x;          // 224 = 16h * 7c * 2b
    int h = blk & 15;
    int q = blk >> 4;              // 0..13
    int c = 1 + (q % 7);
    int b = q / 7;
    int tid = threadIdx.x;

    __shared__ __align__(16) unsigned short Cs_bf[QC][PB];
    __shared__ __align__(16) unsigned short S_bf[QC][PB];
    __shared__ float Eh[QC];

    int bl0 = b * L_SZ + c * QC;
    const float* Zb = Zbuf + ((size_t)(b * NHEADS + h) * NCH) * (HEAD_DIM * D_STATE);
    const float* Eb = Ebuf + ((size_t)(b * NHEADS + h) * NCH) * QC;

    {
        int p = tid >> 2, nq = (tid & 3) * 16;
        float S16[16];
#pragma unroll
        for (int qq = 0; qq < 16; ++qq) S16[qq] = 0.f;
        float wgt = 1.f;
        for (int j = c - 1; j >= 0; --j) {
            const float* Zj = Zb + (size_t)j * (HEAD_DIM * D_STATE) + p * D_STATE + nq;
#pragma unroll
            for (int q4 = 0; q4 < 4; ++q4) {
                float4 z = *(const float4*)(Zj + q4 * 4);
                S16[q4 * 4 + 0] += wgt * z.x;
                S16[q4 * 4 + 1] += wgt * z.y;
                S16[q4 * 4 + 2] += wgt * z.z;
                S16[q4 * 4 + 3] += wgt * z.w;
            }
            wgt *= Eb[(size_t)j * QC + 63];
        }
#pragma unroll
        for (int q4 = 0; q4 < 4; ++q4) {
            ushort4t s4 = {f2bf(S16[q4 * 4 + 0]), f2bf(S16[q4 * 4 + 1]),
                           f2bf(S16[q4 * 4 + 2]), f2bf(S16[q4 * 4 + 3])};
            *(ushort4t*)&S_bf[p][nq + q4 * 4] = s4;
        }
    }

    int row16 = tid >> 4, col4 = (tid & 15) * 4;
#pragma unroll
    for (int r = 0; r < 4; ++r) {
        int t = r * 16 + row16;
        int gl = c * QC + t;
        const unsigned short* xrow = xbc + (size_t)(bl0 + t) * CONV_DIM;
        float4 Cv = conv4b(xrow, gl, D_INNER + D_STATE + col4, conv_w, conv_b);
        ushort4t cq = {f2bf(Cv.x), f2bf(Cv.y), f2bf(Cv.z), f2bf(Cv.w)};
        *(ushort4t*)&Cs_bf[t][col4] = cq;
    }
    if (tid < 64)
        Eh[tid] = Ebuf[(((size_t)(b * NHEADS + h) * NCH) + c) * QC + tid];
    __syncthreads();

    int l = tid & 63, wv = tid >> 6;
    int wm = wv >> 1, wn = wv & 1;
    int fr = l & 15, fq = l >> 4;
    f32x4 acc[2][2];
#pragma unroll
    for (int i = 0; i < 2; ++i)
#pragma unroll
        for (int j = 0; j < 2; ++j) acc[i][j] = (f32x4){0.f, 0.f, 0.f, 0.f};
#pragma unroll
    for (int kk = 0; kk < 2; ++kk) {
        short8t af[2], bb[2];
#pragma unroll
        for (int i = 0; i < 2; ++i)
            af[i] = *(const short8t*)&Cs_bf[wm * 32 + i * 16 + fr][kk * 32 + fq * 8];
#pragma unroll
        for (int j = 0; j < 2; ++j)
            bb[j] = *(const short8t*)&S_bf[wn * 32 + j * 16 + fr][kk * 32 + fq * 8];
#pragma unroll
        for (int i = 0; i < 2; ++i)
#pragma unroll
            for (int j = 0; j < 2; ++j)
                acc[i][j] = __builtin_amdgcn_mfma_f32_16x16x32_bf16(af[i], bb[j], acc[i][j], 0, 0, 0);
    }
#pragma unroll
    for (int i = 0; i < 2; ++i)
#pragma unroll
        for (int j = 0; j < 2; ++j) {
            int p = wn * 32 + j * 16 + fr;
#pragma unroll
            for (int r = 0; r < 4; ++r) {
                int t = wm * 32 + i * 16 + fq * 4 + r;
                float* yp = y + (size_t)(bl0 + t) * D_INNER + h * HEAD_DIM + p;
                *yp += Eh[t] * acc[i][j][r];
            }
        }
}

// ---------------- gate (SiLU(z)) + RMSNorm -> bf16 ----------------
__global__ __launch_bounds__(256) void gated_rmsnorm_kernel(const float* __restrict__ zxbcdt,
                                                            const float* __restrict__ y,
                                                            const float* __restrict__ rms_w,
                                                            unsigned short* __restrict__ yn_bf) {
    int bl = blockIdx.x;
    int tid = threadIdx.x;
    __shared__ float red[4];
    __shared__ float sscale;
    float vals[4];
    float sumsq = 0.f;
#pragma unroll
    for (int i = 0; i < 4; ++i) {
        int col = tid + i * 256;
        float yv = y[(size_t)bl * D_INNER + col];
        float z = zxbcdt[(size_t)bl * D_IN_PROJ + col];
        float yz = yv * (z / (1.f + expf(-z)));
        vals[i] = yz;
        sumsq += yz * yz;
    }
#pragma unroll
    for (int off = 32; off; off >>= 1) sumsq += __shfl_xor(sumsq, off);
    int wave = tid >> 6, lane = tid & 63;
    if (lane == 0) red[wave] = sumsq;
    __syncthreads();
    if (tid == 0) {
        float t = red[0] + red[1] + red[2] + red[3];
        sscale = rsqrtf(t / (float)D_INNER + RMS_EPS);
    }
    __syncthreads();
    float sc = sscale;
#pragma unroll
    for (int i = 0; i < 4; ++i) {
        int col = tid + i * 256;
        yn_bf[(size_t)bl * D_INNER + col] = f2bf(vals[i] * sc * rms_w[col]);
    }
}

// ---------------- launch ----------------
extern "C" void kernel_launch(void* const* d_in, const int* in_sizes, int n_in,
                              void* d_out, int out_size, void* d_ws, size_t ws_size,
                              hipStream_t stream) {
    const float* u       = (const float*)d_in[0];
    const float* W_in    = (const float*)d_in[1];
    const float* conv_w  = (const float*)d_in[2];
    const float* conv_b  = (const float*)d_in[3];
    const float* dt_bias = (const float*)d_in[4];
    const float* A_log   = (const float*)d_in[5];
    const float* D_param = (const float*)d_in[6];
    const float* rms_w   = (const float*)d_in[7];
    const float* W_out   = (const float*)d_in[8];
    float* out = (float*)d_out;

    float* ws = (float*)d_ws;
    float* zxbcdt = ws;                                    // [1024][2192] f32 (z cols only)
    float* y      = zxbcdt + (size_t)BL * D_IN_PROJ;       // [1024][1024] f32
    float* Zbuf   = y + (size_t)BL * D_INNER;              // [32][8][64][64] f32
    float* Ebuf   = Zbuf + (size_t)32 * NCH * 4096;        // [32][8][64] f32
    float* dtb    = Ebuf + (size_t)32 * NCH * QC;          // [1024][16] f32
    unsigned short* u_bf  = (unsigned short*)(dtb + (size_t)BL * 16);  // [1024][512]
    unsigned short* Wt1   = u_bf + (size_t)BL * D_MODEL;               // [2304][512]
    unsigned short* Wt2   = Wt1 + (size_t)NPAD1 * D_MODEL;             // [512][1024]
    unsigned short* yn_bf = Wt2 + (size_t)D_MODEL * D_INNER;           // [1024][1024]
    unsigned short* xbc   = yn_bf + (size_t)BL * D_INNER;              // [1024][1152]

    // 0) convert/transpose weights + u to bf16
    prep_kernel<<<672, 256, 0, stream>>>(W_in, W_out, u, Wt1, Wt2, u_bf);

    // 1) in_proj with split epilogue (z f32 | xBC bf16 compact | dt f32 compact)
    gemm_in<<<dim3(NPAD1 / 64, BL / 64), 256, 0, stream>>>(
        u_bf, Wt1, zxbcdt, xbc, dtb);

    // 2) SSD
    ssd_passA<<<B_SZ * NCH * NHEADS, 256, 0, stream>>>(
        xbc, dtb, conv_w, conv_b, dt_bias, A_log, D_param, y, Zbuf, Ebuf);
    ssd_passC<<<224, 256, 0, stream>>>(
        xbc, conv_w, conv_b, Zbuf, Ebuf, y);

    // 3) gate + RMSNorm -> bf16
    gated_rmsnorm_kernel<<<BL, 256, 0, stream>>>(zxbcdt, y, rms_w, yn_bf);

    // 4) out_proj
    gemm_mfma32<<<dim3(D_MODEL / 64, BL / 32), 256, 0, stream>>>(
        yn_bf, Wt2, out, D_MODEL, D_INNER);
}